// Round 4
// baseline (262.565 us; speedup 1.0000x reference)
//
#include <hip/hip_runtime.h>
#include <hip/hip_bf16.h>

#define ENS 7
#define SDIM 30
#define ADIM 8
#define DIN 38          // SDIM + ADIM
#define HID 200
#define DOUT 31         // SDIM + RDIM
#define NHL 3           // hidden layers
#define HS 232          // hA row stride in elems (116 words -> 2-way max on b128 reads)
#define MT 32           // rows per block

typedef __bf16 bf16x8 __attribute__((ext_vector_type(8)));
typedef float f32x4 __attribute__((ext_vector_type(4)));

// ws layout (ushort elems): bf16 weights pre-swizzled into MFMA fragment order.
// Fragment (ct,st) = contiguous 512-ushort (1024 B) block at (ct*S + st)*512;
// element (lane, j) = W[k = st*32 + (lane>>4)*8 + j][n = ct*16 + (lane&15)]  (0 if OOB)
// Consumed as the MFMA A operand (m = out-col). Wave w owns cts {3w,3w+1,3w+2};
// shared ct12 row-slices go to waves 0,1 (only 2 row-tiles exist at MT=32).
#define U_L1 13312
#define U_H 46592
#define OFF_HD2 (U_L1 + NHL * U_H)            // 153088
#define PER_E (OFF_HD2 + 14336)               // 167424
#define WS_TOTAL (ENS * PER_E)                // 1171968 ushorts = 2.34 MB

__device__ __forceinline__ unsigned short f2bf(float f) {
    unsigned u = __float_as_uint(f);
    u += 0x7fffu + ((u >> 16) & 1u);          // RNE
    return (unsigned short)(u >> 16);
}

__device__ __forceinline__ unsigned pk2(float a, float b) {
    __hip_bfloat162 h = __float22bfloat162_rn(make_float2(a, b));
    return *reinterpret_cast<unsigned*>(&h);
}

__device__ __forceinline__ float softplusf(float x) {
    return fmaxf(x, 0.f) + __logf(1.f + __expf(-fabsf(x)));
}

// ---- prep: fp32 weights -> bf16 fragment-order in ws (layout unchanged since R4) ----
__global__ void prep_kernel(const float* __restrict__ W1, const float* __restrict__ Wh,
                            const float* __restrict__ Wmu, const float* __restrict__ Wsig,
                            unsigned short* __restrict__ ws) {
    int idx = blockIdx.x * 256 + threadIdx.x;
    if (idx >= WS_TOTAL) return;
    int e = idx / PER_E, r = idx % PER_E;
    int j = r & 7, lane = (r >> 3) & 63;
    int l16 = lane & 15, q = lane >> 4;
    float v = 0.f;
    if (r < U_L1) {                            // layer 1 (S=2)
        int fi = r >> 9;
        int ct = fi >> 1, st = fi & 1;
        int k = st * 32 + q * 8 + j, n = ct * 16 + l16;
        if (k < DIN && n < HID) v = W1[(e * DIN + k) * HID + n];
    } else if (r < OFF_HD2) {                  // hidden layers (S=7)
        int rh = r - U_L1;
        int l = rh / U_H, r2 = rh % U_H;
        int fi = r2 >> 9;
        int ct = fi / 7, st = fi % 7;
        int k = st * 32 + q * 8 + j, n = ct * 16 + l16;
        if (k < HID && n < HID) v = Wh[((l * ENS + e) * HID + (long)k) * HID + n];
    } else {                                   // heads (mu cols 0..30, sig cols 32..62)
        int r2 = r - OFF_HD2;
        int fi = r2 >> 9;
        int ct = fi / 7, st = fi % 7;
        int k = st * 32 + q * 8 + j, n = ct * 16 + l16;
        if (k < HID) {
            if (n < DOUT) v = Wmu[(e * HID + k) * DOUT + n];
            else if (n >= 32 && n < 32 + DOUT) v = Wsig[(e * HID + k) * DOUT + (n - 32)];
        }
    }
    ws[idx] = f2bf(v);
}

// One layer. Weights = A operand (SGPR base + single lane offset), activations (LDS)
// = B operand. MT=32 -> 2 row-tiles per wave. `sh` (runtime, wave-uniform): waves 0,1
// additionally own shared ct12 at row-tile=swv.
// R10: one-st-deep weight prefetch (bn) restored, incl. cross-layer st=0 prefetch
// (NS/NOWN/NSH) -- issued before the epilogue so L2 latency hides under swish VALU.
template<int S, int OWN, int NS, int NOWN, bool NSH>
__device__ __forceinline__ void runLayer(const unsigned short* __restrict__ fo,
                                         const unsigned short* __restrict__ fs,
                                         const unsigned short* __restrict__ nfo,
                                         const unsigned short* __restrict__ nfs,
                                         const unsigned short* hA,
                                         int lo, bool sh, int swv, int l16, int quad,
                                         f32x4 (&accO)[2][3], f32x4& accS, bf16x8 (&bq)[4]) {
#pragma unroll
    for (int r = 0; r < 2; r++)
#pragma unroll
        for (int c = 0; c < 3; c++) accO[r][c] = (f32x4){0.f, 0.f, 0.f, 0.f};
    accS = (f32x4){0.f, 0.f, 0.f, 0.f};

#pragma unroll
    for (int st = 0; st < S; ++st) {
        bf16x8 bn[4];
        if (st + 1 < S) {
#pragma unroll
            for (int c = 0; c < OWN; c++) bn[c] = *((const bf16x8*)(fo + (c * S + st + 1) * 512 + lo));
            if (sh) bn[3] = *((const bf16x8*)(fs + (st + 1) * 512 + lo));
        } else if (NS > 0) {
#pragma unroll
            for (int c = 0; c < NOWN; c++) bn[c] = *((const bf16x8*)(nfo + (c * NS) * 512 + lo));
            if (NSH && sh) bn[3] = *((const bf16x8*)(nfs + lo));
        }
        bf16x8 af[2];
#pragma unroll
        for (int r = 0; r < 2; r++)
            af[r] = *((const bf16x8*)(hA + (r * 16 + l16) * HS + st * 32 + quad * 8));
        bf16x8 afs;
        if (sh) afs = *((const bf16x8*)(hA + (swv * 16 + l16) * HS + st * 32 + quad * 8));
#pragma unroll
        for (int c = 0; c < OWN; c++)
#pragma unroll
            for (int r = 0; r < 2; r++)
                accO[r][c] = __builtin_amdgcn_mfma_f32_16x16x32_bf16(bq[c], af[r], accO[r][c], 0, 0, 0);
        if (sh) accS = __builtin_amdgcn_mfma_f32_16x16x32_bf16(bq[3], afs, accS, 0, 0, 0);
        if (st + 1 < S || NS > 0) {
#pragma unroll
            for (int c = 0; c < 4; c++) bq[c] = bn[c];
        }
    }
}

// ---- fused 5-layer ensemble MLP ----
// R9 post-mortem: 60% occupancy spill-free did NOT beat the 31%-occ prefetch baseline
// -> kernel is L2-latency-bound on the weight stream, not occupancy-bound.
// R10: prefetch restored (fits: acc=28 now) + same-e block clustering for L1/L2 reuse.
__launch_bounds__(256, 4)
__global__ void ens_mlp_kernel(const float* __restrict__ s, const float* __restrict__ a,
                               const float* __restrict__ b1, const float* __restrict__ bh,
                               const float* __restrict__ bmu, const float* __restrict__ bsig,
                               const float* __restrict__ maxs, const float* __restrict__ mins,
                               const float* __restrict__ maxr, const float* __restrict__ minr,
                               const unsigned short* __restrict__ ws,
                               float* __restrict__ out, int N) {
    __shared__ unsigned short hA[MT * HS];     // 14848 B, activations (bf16) -- only LDS

    const int tid = threadIdx.x;
    const int wv = tid >> 6, lane = tid & 63;
    const int quad = lane >> 4, l16 = lane & 15;
    const int swv = __builtin_amdgcn_readfirstlane(wv);   // wave-uniform -> SGPR addressing
    const bool sh = (swv < 2);                 // waves 0,1 own shared ct12 (row-tile=swv)
    const int lo = lane * 8;                   // single per-lane weight offset (elems)
    const int bid = blockIdx.x;
    // R10: same-e clustering -- consecutive blocks share the weight stream (L1/L2 hot)
    const int bpe = (int)((unsigned)N / MT);   // blocks per ensemble (1024)
    const int e = bid / bpe, n0 = (bid % bpe) * MT;

    // zero ONLY the K-pad cols: [38,64) for layer 1, [208,232) for hidden/head layers.
    // All other cols are written (staged or epilogue) before any read. (R10: was full-LDS)
    for (int t = tid; t < 32 * 13; t += 256) {
        int row = t / 13, k = t % 13;
        *((unsigned*)(hA + row * HS + 38 + 2 * k)) = 0u;
    }
    for (int t = tid; t < 32 * 12; t += 256) {
        int row = t / 12, k = t % 12;
        *((unsigned*)(hA + row * HS + 208 + 2 * k)) = 0u;
    }

    // stage x = concat(s, a) -> hA cols 0..37 (bf16); disjoint from pad cols, no barrier
    {
        int m = tid & 31, cg = tid >> 5;
        long g = n0 + m;
        const float* srow = s + (g * ENS + e) * SDIM;
        const float* arow = a + (g * ENS + e) * ADIM;
#pragma unroll
        for (int k = 0; k < 5; k++) {
            int c = cg * 5 + k;
            if (c < DIN) {
                float v = (c < SDIM) ? srow[c] : arow[c - SDIM];
                hA[m * HS + c] = f2bf(v);
            }
        }
    }
    __syncthreads();

    // wave-uniform fragment base pointers (SGPR; per-lane part is `lo`)
    const unsigned short* we = ws + e * PER_E;
    const unsigned short* L1o = we + swv * 3 * 2 * 512;
    const unsigned short* L1s = we + 12 * 2 * 512;
    const unsigned short* H0o = we + U_L1 + swv * 3 * 7 * 512;
    const unsigned short* H0s = we + U_L1 + 12 * 7 * 512;
    const unsigned short* H1o = H0o + U_H;
    const unsigned short* H1s = H0s + U_H;
    const unsigned short* H2o = H1o + U_H;
    const unsigned short* H2s = H1s + U_H;
    const unsigned short* HDo = we + OFF_HD2 + swv * 7 * 512;

    f32x4 accO[2][3];   // own col-tiles: [row-tile][c]
    f32x4 accS;         // shared ct12, row-tile = swv (waves 0,1 only)
    bf16x8 bq[4];

    // bias + swish -> hA. Own cts: col < 192 always (unconditional float4 bias).
    // Shared ct12: cols 192..207; pad cols (>=200) have zero weights+bias -> writes 0,
    // which is exactly the K-pad zero the next layer needs.
    auto epiH = [&](const float* bias) {
#pragma unroll
        for (int c = 0; c < 3; c++) {
            int col = (3 * swv + c) * 16 + quad * 4;
            float4 bc4 = *((const float4*)(bias + col));
#pragma unroll
            for (int r = 0; r < 2; r++) {
                float v0 = accO[r][c][0] + bc4.x, v1 = accO[r][c][1] + bc4.y;
                float v2 = accO[r][c][2] + bc4.z, v3 = accO[r][c][3] + bc4.w;
                v0 *= __builtin_amdgcn_rcpf(1.f + __expf(-v0));
                v1 *= __builtin_amdgcn_rcpf(1.f + __expf(-v1));
                v2 *= __builtin_amdgcn_rcpf(1.f + __expf(-v2));
                v3 *= __builtin_amdgcn_rcpf(1.f + __expf(-v3));
                *((uint2*)(hA + (r * 16 + l16) * HS + col)) = make_uint2(pk2(v0, v1), pk2(v2, v3));
            }
        }
        if (sh) {
            int col = 192 + quad * 4;
            float4 bc4 = make_float4(0.f, 0.f, 0.f, 0.f);
            if (col < HID) bc4 = *((const float4*)(bias + col));   // quad 0,1 only
            float v0 = accS[0] + bc4.x, v1 = accS[1] + bc4.y;
            float v2 = accS[2] + bc4.z, v3 = accS[3] + bc4.w;
            v0 *= __builtin_amdgcn_rcpf(1.f + __expf(-v0));
            v1 *= __builtin_amdgcn_rcpf(1.f + __expf(-v1));
            v2 *= __builtin_amdgcn_rcpf(1.f + __expf(-v2));
            v3 *= __builtin_amdgcn_rcpf(1.f + __expf(-v3));
            *((uint2*)(hA + (swv * 16 + l16) * HS + col)) = make_uint2(pk2(v0, v1), pk2(v2, v3));
        }
    };

    // initial fragment load (L1, st=0)
#pragma unroll
    for (int c = 0; c < 3; c++) bq[c] = *((const bf16x8*)(L1o + (c * 2) * 512 + lo));
    if (sh) bq[3] = *((const bf16x8*)(L1s + lo));

    runLayer<2, 3, 7, 3, true>(L1o, L1s, H0o, H0s, hA, lo, sh, swv, l16, quad, accO, accS, bq);
    __syncthreads();
    epiH(b1 + e * HID);
    __syncthreads();
    runLayer<7, 3, 7, 3, true>(H0o, H0s, H1o, H1s, hA, lo, sh, swv, l16, quad, accO, accS, bq);
    __syncthreads();
    epiH(bh + (0 * ENS + e) * HID);
    __syncthreads();
    runLayer<7, 3, 7, 3, true>(H1o, H1s, H2o, H2s, hA, lo, sh, swv, l16, quad, accO, accS, bq);
    __syncthreads();
    epiH(bh + (1 * ENS + e) * HID);
    __syncthreads();
    runLayer<7, 3, 7, 1, false>(H2o, H2s, HDo, (const unsigned short*)nullptr,
                                hA, lo, sh, swv, l16, quad, accO, accS, bq);
    __syncthreads();
    epiH(bh + (2 * ENS + e) * HID);
    __syncthreads();
    runLayer<7, 1, 0, 0, false>(HDo, (const unsigned short*)nullptr,
                                (const unsigned short*)nullptr, (const unsigned short*)nullptr,
                                hA, lo, false, swv, l16, quad, accO, accS, bq);
    // no barrier: head tail reads only registers, writes only global

    // head tail: wave owns ct = swv -> lane holds cols swv*16+quad*4+{0..3}
    // (mu block 0..31 for swv<2, sigma block 32..63 for swv>=2), rows r*16+l16.
    const long off1 = (long)N * ENS * SDIM;    // ds_sg
    const long off2 = 2 * off1;                // r_mu
    const long off3 = off2 + (long)N * ENS;    // r_sg
    {
        const bool isSig = (swv >= 2);
        const int c0 = (swv & 1) * 16 + quad * 4;
        float bias_i[4], mx_i[4], mn_i[4];
#pragma unroll
        for (int i = 0; i < 4; i++) {
            int c = c0 + i;
            bias_i[i] = (c < DOUT) ? (isSig ? bsig : bmu)[e * DOUT + c] : 0.f;
            if (isSig) {
                mx_i[i] = (c < SDIM) ? maxs[c] : maxr[0];
                mn_i[i] = (c < SDIM) ? mins[c] : minr[0];
            }
        }
#pragma unroll
        for (int r = 0; r < 2; r++) {
            long g = n0 + r * 16 + l16;
            long rowbase = (g * ENS + e) * SDIM;
#pragma unroll
            for (int i = 0; i < 4; i++) {
                int c = c0 + i;
                if (c < DOUT) {
                    float v = accO[r][0][i] + bias_i[i];
                    if (!isSig) {
                        if (c < SDIM) out[rowbase + c] = v;
                        else out[off2 + g * ENS + e] = v;
                    } else {
                        v = 0.5f * (mx_i[i] - softplusf(mx_i[i] - 2.f * v));
                        v = 0.5f * (mn_i[i] + softplusf(2.f * v - mn_i[i]));
                        v = __expf(v);
                        if (c < SDIM) out[off1 + rowbase + c] = v;
                        else out[off3 + g * ENS + e] = v;
                    }
                }
            }
        }
    }
}

extern "C" void kernel_launch(void* const* d_in, const int* in_sizes, int n_in,
                              void* d_out, int out_size, void* d_ws, size_t ws_size,
                              hipStream_t stream) {
    const float* s    = (const float*)d_in[0];
    const float* a    = (const float*)d_in[1];
    const float* W1   = (const float*)d_in[2];
    const float* b1   = (const float*)d_in[3];
    const float* Wh   = (const float*)d_in[4];
    const float* bh   = (const float*)d_in[5];
    const float* Wmu  = (const float*)d_in[6];
    const float* bmu  = (const float*)d_in[7];
    const float* Wsig = (const float*)d_in[8];
    const float* bsig = (const float*)d_in[9];
    const float* maxs = (const float*)d_in[10];
    const float* mins = (const float*)d_in[11];
    const float* maxr = (const float*)d_in[12];
    const float* minr = (const float*)d_in[13];
    float* out = (float*)d_out;
    unsigned short* ws = (unsigned short*)d_ws;

    int N = in_sizes[0] / (ENS * SDIM);        // 32768

    int prepBlocks = (WS_TOTAL + 255) / 256;
    prep_kernel<<<prepBlocks, 256, 0, stream>>>(W1, Wh, Wmu, Wsig, ws);

    int mainBlocks = (N / MT) * ENS;           // 7168
    ens_mlp_kernel<<<mainBlocks, 256, 0, stream>>>(s, a, b1, bh, bmu, bsig,
                                                   maxs, mins, maxr, minr, ws, out, N);
}

// Round 6
// 252.048 us; speedup vs baseline: 1.0417x; 1.0417x over previous
//
#include <hip/hip_runtime.h>
#include <hip/hip_bf16.h>

#define ENS 7
#define SDIM 30
#define ADIM 8
#define DIN 38          // SDIM + ADIM
#define HID 200
#define DOUT 31         // SDIM + RDIM
#define NHL 3           // hidden layers
#define HS 232          // hA row stride in elems (116 words -> 2-way max on b128 reads)
#define MT 64           // rows per block (R11: back to R6 geometry -- best measured)

typedef __bf16 bf16x8 __attribute__((ext_vector_type(8)));
typedef float f32x4 __attribute__((ext_vector_type(4)));

// ws layout (ushort elems): bf16 weights pre-swizzled into MFMA fragment order.
// Fragment (ct,st) = contiguous 512-ushort (1024 B) block at (ct*S + st)*512;
// element (lane, j) = W[k = st*32 + (lane>>4)*8 + j][n = ct*16 + (lane&15)]  (0 if OOB)
// Consumed as the MFMA A operand (m = out-col). Ownership (NT=13): wave w owns
// cts {3w,3w+1,3w+2} fully + row-slice rt=w of ct 12  -> perfect 13/13/13/13 balance.
#define U_L1 13312
#define U_H 46592
#define OFF_HD2 (U_L1 + NHL * U_H)            // 153088
#define PER_E (OFF_HD2 + 14336)               // 167424
#define WS_TOTAL (ENS * PER_E)                // 1171968 ushorts = 2.34 MB

__device__ __forceinline__ unsigned short f2bf(float f) {
    unsigned u = __float_as_uint(f);
    u += 0x7fffu + ((u >> 16) & 1u);          // RNE
    return (unsigned short)(u >> 16);
}

__device__ __forceinline__ unsigned pk2(float a, float b) {
    __hip_bfloat162 h = __float22bfloat162_rn(make_float2(a, b));
    return *reinterpret_cast<unsigned*>(&h);
}

__device__ __forceinline__ float softplusf(float x) {
    return fmaxf(x, 0.f) + __logf(1.f + __expf(-fabsf(x)));
}

// ---- prep: fp32 weights -> bf16 fragment-order in ws (layout unchanged since R4) ----
__global__ void prep_kernel(const float* __restrict__ W1, const float* __restrict__ Wh,
                            const float* __restrict__ Wmu, const float* __restrict__ Wsig,
                            unsigned short* __restrict__ ws) {
    int idx = blockIdx.x * 256 + threadIdx.x;
    if (idx >= WS_TOTAL) return;
    int e = idx / PER_E, r = idx % PER_E;
    int j = r & 7, lane = (r >> 3) & 63;
    int l16 = lane & 15, q = lane >> 4;
    float v = 0.f;
    if (r < U_L1) {                            // layer 1 (S=2)
        int fi = r >> 9;
        int ct = fi >> 1, st = fi & 1;
        int k = st * 32 + q * 8 + j, n = ct * 16 + l16;
        if (k < DIN && n < HID) v = W1[(e * DIN + k) * HID + n];
    } else if (r < OFF_HD2) {                  // hidden layers (S=7)
        int rh = r - U_L1;
        int l = rh / U_H, r2 = rh % U_H;
        int fi = r2 >> 9;
        int ct = fi / 7, st = fi % 7;
        int k = st * 32 + q * 8 + j, n = ct * 16 + l16;
        if (k < HID && n < HID) v = Wh[((l * ENS + e) * HID + (long)k) * HID + n];
    } else {                                   // heads (mu cols 0..30, sig cols 32..62)
        int r2 = r - OFF_HD2;
        int fi = r2 >> 9;
        int ct = fi / 7, st = fi % 7;
        int k = st * 32 + q * 8 + j, n = ct * 16 + l16;
        if (k < HID) {
            if (n < DOUT) v = Wmu[(e * HID + k) * DOUT + n];
            else if (n >= 32 && n < 32 + DOUT) v = Wsig[(e * HID + k) * DOUT + (n - 32)];
        }
    }
    ws[idx] = f2bf(v);
}

// One layer, balanced ownership. Weights = A operand (SGPR base + single lane offset),
// activations (LDS) = B operand. D[m = out-col][n = batch-row].
// R11: prefetch double-buffer is a compile-time PING-PONG (cur/nxt roles swap per st
// after full unroll) -- no bq<-bn register copies (R10's VALU regression).
// Parity: S=2 -> in X out X; S=7 -> in X out Y (caller alternates buffer order).
// Cross-layer st=0 prefetch (NS/NOWN/NSH) issues before the epilogue barriers so L2
// latency hides under swish VALU.
template<int S, int OWN, bool SH, int NS, int NOWN, bool NSH>
__device__ __forceinline__ void runLayer(const unsigned short* __restrict__ fo,
                                         const unsigned short* __restrict__ fs,
                                         const unsigned short* __restrict__ nfo,
                                         const unsigned short* __restrict__ nfs,
                                         const unsigned short* hA,
                                         int lo, int swv, int l16, int quad,
                                         f32x4 (&accO)[4][3], f32x4& accS,
                                         bf16x8 (&bq)[4], bf16x8 (&bt)[4]) {
#pragma unroll
    for (int r = 0; r < 4; r++)
#pragma unroll
        for (int c = 0; c < 3; c++) accO[r][c] = (f32x4){0.f, 0.f, 0.f, 0.f};
    accS = (f32x4){0.f, 0.f, 0.f, 0.f};

    auto body = [&](bf16x8 (&cur)[4], bf16x8 (&nxt)[4], int st) {
        if (st + 1 < S) {
#pragma unroll
            for (int c = 0; c < OWN; c++) nxt[c] = *((const bf16x8*)(fo + (c * S + st + 1) * 512 + lo));
            if (SH) nxt[3] = *((const bf16x8*)(fs + (st + 1) * 512 + lo));
        } else if (NS > 0) {
#pragma unroll
            for (int c = 0; c < NOWN; c++) nxt[c] = *((const bf16x8*)(nfo + (c * NS) * 512 + lo));
            if (NSH) nxt[3] = *((const bf16x8*)(nfs + lo));
        }
        bf16x8 af[4];
#pragma unroll
        for (int r = 0; r < 4; r++)
            af[r] = *((const bf16x8*)(hA + (r * 16 + l16) * HS + st * 32 + quad * 8));
        bf16x8 afs;
        if (SH) afs = *((const bf16x8*)(hA + (swv * 16 + l16) * HS + st * 32 + quad * 8));
#pragma unroll
        for (int c = 0; c < OWN; c++)
#pragma unroll
            for (int r = 0; r < 4; r++)
                accO[r][c] = __builtin_amdgcn_mfma_f32_16x16x32_bf16(cur[c], af[r], accO[r][c], 0, 0, 0);
        if (SH) accS = __builtin_amdgcn_mfma_f32_16x16x32_bf16(cur[3], afs, accS, 0, 0, 0);
    };

#pragma unroll
    for (int st = 0; st < S; ++st) {
        if ((st & 1) == 0) body(bq, bt, st);
        else               body(bt, bq, st);
    }
}

// ---- fused 5-layer ensemble MLP ----
// R7-R10 post-mortems: occupancy (31->60%) does not correlate with time; fetch volume
// (88->38 MB) does not correlate with time. Best structure is R6's: MT=64, (256,3),
// one-st prefetch. R11 = R6 + e-clustering + SGPR weight bases + ping-pong prefetch
// (no copies) + partial pad-zeroing.
__launch_bounds__(256, 3)
__global__ void ens_mlp_kernel(const float* __restrict__ s, const float* __restrict__ a,
                               const float* __restrict__ b1, const float* __restrict__ bh,
                               const float* __restrict__ bmu, const float* __restrict__ bsig,
                               const float* __restrict__ maxs, const float* __restrict__ mins,
                               const float* __restrict__ maxr, const float* __restrict__ minr,
                               const unsigned short* __restrict__ ws,
                               float* __restrict__ out, int N) {
    __shared__ unsigned short hA[MT * HS];     // 29696 B, activations (bf16) -- only LDS

    const int tid = threadIdx.x;
    const int wv = tid >> 6, lane = tid & 63;
    const int quad = lane >> 4, l16 = lane & 15;
    const int swv = __builtin_amdgcn_readfirstlane(wv);   // wave-uniform -> SGPR addressing
    const int lo = lane * 8;                   // single per-lane weight offset (elems)
    const int bid = blockIdx.x;
    // e-clustering: consecutive blocks share one ensemble's weight stream (L1/L2 hot).
    // R10 evidence: FETCH 71->38 MB at MT=32.
    const int bpe = N / MT;                    // blocks per ensemble (512)
    const int e = bid / bpe, n0 = (bid - e * bpe) * MT;

    // zero ONLY the K-pad cols: [38,64) and [208,232). All other cols are written
    // (staged or epilogue) before any read.
    for (int t = tid; t < MT * 13; t += 256) {
        int row = t / 13, k = t - row * 13;
        *((unsigned*)(hA + row * HS + 38 + 2 * k)) = 0u;
    }
    for (int t = tid; t < MT * 12; t += 256) {
        int row = t / 12, k = t - row * 12;
        *((unsigned*)(hA + row * HS + 208 + 2 * k)) = 0u;
    }

    // stage x = concat(s, a) -> hA cols 0..37 (bf16); disjoint from pad cols
    {
        int m = tid & 63, cg = tid >> 6;
        long g = n0 + m;
        const float* srow = s + (g * ENS + e) * SDIM;
        const float* arow = a + (g * ENS + e) * ADIM;
#pragma unroll
        for (int k = 0; k < 10; k++) {
            int c = cg * 10 + k;
            if (c < DIN) {
                float v = (c < SDIM) ? srow[c] : arow[c - SDIM];
                hA[m * HS + c] = f2bf(v);
            }
        }
    }
    __syncthreads();

    // wave-uniform fragment base pointers (SGPR; per-lane part is `lo`)
    const unsigned short* we = ws + e * PER_E;
    const unsigned short* L1o = we + swv * 3 * 2 * 512;
    const unsigned short* L1s = we + 12 * 2 * 512;
    const unsigned short* H0o = we + U_L1 + swv * 3 * 7 * 512;
    const unsigned short* H0s = we + U_L1 + 12 * 7 * 512;
    const unsigned short* H1o = H0o + U_H;
    const unsigned short* H1s = H0s + U_H;
    const unsigned short* H2o = H1o + U_H;
    const unsigned short* H2s = H1s + U_H;
    const unsigned short* HDo = we + OFF_HD2 + swv * 7 * 512;

    f32x4 accO[4][3];   // own col-tiles: [row-tile][c]
    f32x4 accS;         // shared ct12, row-tile = swv
    bf16x8 bqA[4], bqB[4];   // ping-pong weight fragment buffers

    // bias + swish -> hA. Own cts: col < 192 always (unconditional float4 bias).
    // Shared ct12: cols 192..207; pad cols (>=200) have zero weights+bias -> writes 0,
    // which is exactly the K-pad zero the next layer needs.
    auto epiH = [&](const float* bias) {
#pragma unroll
        for (int c = 0; c < 3; c++) {
            int col = (3 * swv + c) * 16 + quad * 4;
            float4 bc4 = *((const float4*)(bias + col));
#pragma unroll
            for (int r = 0; r < 4; r++) {
                float v0 = accO[r][c][0] + bc4.x, v1 = accO[r][c][1] + bc4.y;
                float v2 = accO[r][c][2] + bc4.z, v3 = accO[r][c][3] + bc4.w;
                v0 *= __builtin_amdgcn_rcpf(1.f + __expf(-v0));
                v1 *= __builtin_amdgcn_rcpf(1.f + __expf(-v1));
                v2 *= __builtin_amdgcn_rcpf(1.f + __expf(-v2));
                v3 *= __builtin_amdgcn_rcpf(1.f + __expf(-v3));
                *((uint2*)(hA + (r * 16 + l16) * HS + col)) = make_uint2(pk2(v0, v1), pk2(v2, v3));
            }
        }
        {
            int col = 192 + quad * 4;
            float4 bc4 = make_float4(0.f, 0.f, 0.f, 0.f);
            if (col < HID) bc4 = *((const float4*)(bias + col));   // quad 0,1 only
            float v0 = accS[0] + bc4.x, v1 = accS[1] + bc4.y;
            float v2 = accS[2] + bc4.z, v3 = accS[3] + bc4.w;
            v0 *= __builtin_amdgcn_rcpf(1.f + __expf(-v0));
            v1 *= __builtin_amdgcn_rcpf(1.f + __expf(-v1));
            v2 *= __builtin_amdgcn_rcpf(1.f + __expf(-v2));
            v3 *= __builtin_amdgcn_rcpf(1.f + __expf(-v3));
            *((uint2*)(hA + (swv * 16 + l16) * HS + col)) = make_uint2(pk2(v0, v1), pk2(v2, v3));
        }
    };

    // initial fragment load (L1, st=0) -> bqA
#pragma unroll
    for (int c = 0; c < 3; c++) bqA[c] = *((const bf16x8*)(L1o + (c * 2) * 512 + lo));
    bqA[3] = *((const bf16x8*)(L1s + lo));

    // Buffer parity chain: L1(S=2) in A out A; each S=7 layer flips.
    runLayer<2, 3, true, 7, 3, true>(L1o, L1s, H0o, H0s, hA, lo, swv, l16, quad, accO, accS, bqA, bqB);
    __syncthreads();
    epiH(b1 + e * HID);
    __syncthreads();
    runLayer<7, 3, true, 7, 3, true>(H0o, H0s, H1o, H1s, hA, lo, swv, l16, quad, accO, accS, bqA, bqB);
    __syncthreads();
    epiH(bh + (0 * ENS + e) * HID);
    __syncthreads();
    runLayer<7, 3, true, 7, 3, true>(H1o, H1s, H2o, H2s, hA, lo, swv, l16, quad, accO, accS, bqB, bqA);
    __syncthreads();
    epiH(bh + (1 * ENS + e) * HID);
    __syncthreads();
    runLayer<7, 3, true, 7, 1, false>(H2o, H2s, HDo, (const unsigned short*)nullptr,
                                      hA, lo, swv, l16, quad, accO, accS, bqA, bqB);
    __syncthreads();
    epiH(bh + (2 * ENS + e) * HID);
    __syncthreads();
    runLayer<7, 1, false, 0, 0, false>(HDo, (const unsigned short*)nullptr,
                                       (const unsigned short*)nullptr, (const unsigned short*)nullptr,
                                       hA, lo, swv, l16, quad, accO, accS, bqB, bqA);
    // no barrier: head tail reads only registers, writes only global

    // head tail: wave owns ct = swv -> lane holds cols swv*16+quad*4+{0..3}
    // (mu block 0..31 for swv<2, sigma block 32..63 for swv>=2), rows r*16+l16.
    const long off1 = (long)N * ENS * SDIM;    // ds_sg
    const long off2 = 2 * off1;                // r_mu
    const long off3 = off2 + (long)N * ENS;    // r_sg
    {
        const bool isSig = (swv >= 2);
        const int c0 = (swv & 1) * 16 + quad * 4;
        float bias_i[4], mx_i[4], mn_i[4];
#pragma unroll
        for (int i = 0; i < 4; i++) {
            int c = c0 + i;
            bias_i[i] = (c < DOUT) ? (isSig ? bsig : bmu)[e * DOUT + c] : 0.f;
            if (isSig) {
                mx_i[i] = (c < SDIM) ? maxs[c] : maxr[0];
                mn_i[i] = (c < SDIM) ? mins[c] : minr[0];
            }
        }
#pragma unroll
        for (int r = 0; r < 4; r++) {
            long g = n0 + r * 16 + l16;
            long rowbase = (g * ENS + e) * SDIM;
#pragma unroll
            for (int i = 0; i < 4; i++) {
                int c = c0 + i;
                if (c < DOUT) {
                    float v = accO[r][0][i] + bias_i[i];
                    if (!isSig) {
                        if (c < SDIM) out[rowbase + c] = v;
                        else out[off2 + g * ENS + e] = v;
                    } else {
                        v = 0.5f * (mx_i[i] - softplusf(mx_i[i] - 2.f * v));
                        v = 0.5f * (mn_i[i] + softplusf(2.f * v - mn_i[i]));
                        v = __expf(v);
                        if (c < SDIM) out[off1 + rowbase + c] = v;
                        else out[off3 + g * ENS + e] = v;
                    }
                }
            }
        }
    }
}

extern "C" void kernel_launch(void* const* d_in, const int* in_sizes, int n_in,
                              void* d_out, int out_size, void* d_ws, size_t ws_size,
                              hipStream_t stream) {
    const float* s    = (const float*)d_in[0];
    const float* a    = (const float*)d_in[1];
    const float* W1   = (const float*)d_in[2];
    const float* b1   = (const float*)d_in[3];
    const float* Wh   = (const float*)d_in[4];
    const float* bh   = (const float*)d_in[5];
    const float* Wmu  = (const float*)d_in[6];
    const float* bmu  = (const float*)d_in[7];
    const float* Wsig = (const float*)d_in[8];
    const float* bsig = (const float*)d_in[9];
    const float* maxs = (const float*)d_in[10];
    const float* mins = (const float*)d_in[11];
    const float* maxr = (const float*)d_in[12];
    const float* minr = (const float*)d_in[13];
    float* out = (float*)d_out;
    unsigned short* ws = (unsigned short*)d_ws;

    int N = in_sizes[0] / (ENS * SDIM);        // 32768

    int prepBlocks = (WS_TOTAL + 255) / 256;
    prep_kernel<<<prepBlocks, 256, 0, stream>>>(W1, Wh, Wmu, Wsig, ws);

    int mainBlocks = (N / MT) * ENS;           // 3584
    ens_mlp_kernel<<<mainBlocks, 256, 0, stream>>>(s, a, b1, bh, bmu, bsig,
                                                   maxs, mins, maxr, minr, ws, out, N);
}

// Round 8
// 227.364 us; speedup vs baseline: 1.1548x; 1.1086x over previous
//
#include <hip/hip_runtime.h>
#include <hip/hip_bf16.h>

#define ENS 7
#define SDIM 30
#define ADIM 8
#define DIN 38          // SDIM + ADIM
#define HID 200
#define DOUT 31         // SDIM + RDIM
#define NHL 3           // hidden layers
#define HS 232          // hA row stride in elems (116 words -> 2-way max on b128 reads)
#define MT 64           // rows per block

typedef __bf16 bf16x8 __attribute__((ext_vector_type(8)));
typedef float f32x4 __attribute__((ext_vector_type(4)));

// ws layout (ushort elems): bf16 weights pre-swizzled into MFMA fragment order.
// Fragment (ct,st) = contiguous 512-ushort (1024 B) block at (ct*S + st)*512;
// element (lane, j) = W[k = st*32 + (lane>>4)*8 + j][n = ct*16 + (lane&15)]  (0 if OOB)
// Consumed as the MFMA A operand (m = out-col). Ownership (NT=13): wave w owns
// cts {3w,3w+1,3w+2} fully + row-slice rt=w of ct 12  -> perfect 13/13/13/13 balance.
#define U_L1 13312
#define U_H 46592
#define OFF_HD2 (U_L1 + NHL * U_H)            // 153088
#define PER_E (OFF_HD2 + 14336)               // 167424
#define WS_TOTAL (ENS * PER_E)                // 1171968 ushorts = 2.34 MB

__device__ __forceinline__ unsigned short f2bf(float f) {
    unsigned u = __float_as_uint(f);
    u += 0x7fffu + ((u >> 16) & 1u);          // RNE
    return (unsigned short)(u >> 16);
}

__device__ __forceinline__ unsigned pk2(float a, float b) {
    __hip_bfloat162 h = __float22bfloat162_rn(make_float2(a, b));
    return *reinterpret_cast<unsigned*>(&h);
}

__device__ __forceinline__ float softplusf(float x) {
    return fmaxf(x, 0.f) + __logf(1.f + __expf(-fabsf(x)));
}

// ---- prep: fp32 weights -> bf16 fragment-order in ws (layout unchanged since R4) ----
__global__ void prep_kernel(const float* __restrict__ W1, const float* __restrict__ Wh,
                            const float* __restrict__ Wmu, const float* __restrict__ Wsig,
                            unsigned short* __restrict__ ws) {
    int idx = blockIdx.x * 256 + threadIdx.x;
    if (idx >= WS_TOTAL) return;
    int e = idx / PER_E, r = idx % PER_E;
    int j = r & 7, lane = (r >> 3) & 63;
    int l16 = lane & 15, q = lane >> 4;
    float v = 0.f;
    if (r < U_L1) {                            // layer 1 (S=2)
        int fi = r >> 9;
        int ct = fi >> 1, st = fi & 1;
        int k = st * 32 + q * 8 + j, n = ct * 16 + l16;
        if (k < DIN && n < HID) v = W1[(e * DIN + k) * HID + n];
    } else if (r < OFF_HD2) {                  // hidden layers (S=7)
        int rh = r - U_L1;
        int l = rh / U_H, r2 = rh % U_H;
        int fi = r2 >> 9;
        int ct = fi / 7, st = fi % 7;
        int k = st * 32 + q * 8 + j, n = ct * 16 + l16;
        if (k < HID && n < HID) v = Wh[((l * ENS + e) * HID + (long)k) * HID + n];
    } else {                                   // heads (mu cols 0..30, sig cols 32..62)
        int r2 = r - OFF_HD2;
        int fi = r2 >> 9;
        int ct = fi / 7, st = fi % 7;
        int k = st * 32 + q * 8 + j, n = ct * 16 + l16;
        if (k < HID) {
            if (n < DOUT) v = Wmu[(e * HID + k) * DOUT + n];
            else if (n >= 32 && n < 32 + DOUT) v = Wsig[(e * HID + k) * DOUT + (n - 32)];
        }
    }
    ws[idx] = f2bf(v);
}

// One layer, balanced ownership. Weights = A operand (SGPR base + single lane offset),
// activations (LDS) = B operand. D[m = out-col][n = batch-row].
// R12 changes vs R11:
//  - acc initialized from BIAS (iO/iS), not zero -> epilogue bias adds deleted.
//  - afs LDS read deleted: shared-ct12 B-fragment == af[swv]; selected via a
//    wave-uniform `if (swv == r)` in the unrolled r-loop (-20% of LDS reads).
// Ping-pong prefetch (R11) unchanged: cur/nxt roles alternate per st, no reg copies;
// cross-layer st=0 prefetch (NS/NOWN/NSH) issues before the epilogue barriers.
template<int S, int OWN, bool SH, int NS, int NOWN, bool NSH>
__device__ __forceinline__ void runLayer(const unsigned short* __restrict__ fo,
                                         const unsigned short* __restrict__ fs,
                                         const unsigned short* __restrict__ nfo,
                                         const unsigned short* __restrict__ nfs,
                                         const unsigned short* hA,
                                         int lo, int swv, int l16, int quad,
                                         f32x4 (&accO)[4][3], f32x4& accS,
                                         bf16x8 (&bq)[4], bf16x8 (&bt)[4],
                                         const f32x4 (&iO)[3], const f32x4 iS) {
#pragma unroll
    for (int r = 0; r < 4; r++)
#pragma unroll
        for (int c = 0; c < 3; c++) accO[r][c] = iO[c];
    accS = iS;

    auto body = [&](bf16x8 (&cur)[4], bf16x8 (&nxt)[4], int st) {
        if (st + 1 < S) {
#pragma unroll
            for (int c = 0; c < OWN; c++) nxt[c] = *((const bf16x8*)(fo + (c * S + st + 1) * 512 + lo));
            if (SH) nxt[3] = *((const bf16x8*)(fs + (st + 1) * 512 + lo));
        } else if (NS > 0) {
#pragma unroll
            for (int c = 0; c < NOWN; c++) nxt[c] = *((const bf16x8*)(nfo + (c * NS) * 512 + lo));
            if (NSH) nxt[3] = *((const bf16x8*)(nfs + lo));
        }
        bf16x8 af[4];
#pragma unroll
        for (int r = 0; r < 4; r++)
            af[r] = *((const bf16x8*)(hA + (r * 16 + l16) * HS + st * 32 + quad * 8));
#pragma unroll
        for (int c = 0; c < OWN; c++)
#pragma unroll
            for (int r = 0; r < 4; r++)
                accO[r][c] = __builtin_amdgcn_mfma_f32_16x16x32_bf16(cur[c], af[r], accO[r][c], 0, 0, 0);
        if (SH) {
#pragma unroll
            for (int r = 0; r < 4; r++)
                if (swv == r)   // wave-uniform scalar branch; af[swv] == old afs data
                    accS = __builtin_amdgcn_mfma_f32_16x16x32_bf16(cur[3], af[r], accS, 0, 0, 0);
        }
    };

#pragma unroll
    for (int st = 0; st < S; ++st) {
        if ((st & 1) == 0) body(bq, bt, st);
        else               body(bt, bq, st);
    }
}

// ---- fused 5-layer ensemble MLP ----
// R6-R11 post-mortems: occupancy (31->60%), fetch volume (38->113 MB) uncorrelated
// with time; VALU issue (~77us) and LDS pipe (~69us incl 1.2e7 conflict cyc) are the
// busy pipes. R12 = instruction diet: bias-folded acc init, afs read deleted,
// pair-packed staging. Geometry fixed: MT=64, (256,3), e-clustering, ping-pong.
__launch_bounds__(256, 3)
__global__ void ens_mlp_kernel(const float* __restrict__ s, const float* __restrict__ a,
                               const float* __restrict__ b1, const float* __restrict__ bh,
                               const float* __restrict__ bmu, const float* __restrict__ bsig,
                               const float* __restrict__ maxs, const float* __restrict__ mins,
                               const float* __restrict__ maxr, const float* __restrict__ minr,
                               const unsigned short* __restrict__ ws,
                               float* __restrict__ out, int N) {
    __shared__ unsigned short hA[MT * HS];     // 29696 B, activations (bf16) -- only LDS

    const int tid = threadIdx.x;
    const int wv = tid >> 6, lane = tid & 63;
    const int quad = lane >> 4, l16 = lane & 15;
    const int swv = __builtin_amdgcn_readfirstlane(wv);   // wave-uniform -> SGPR addressing
    const int lo = lane * 8;                   // single per-lane weight offset (elems)
    const int bid = blockIdx.x;
    // e-clustering: consecutive blocks share one ensemble's weight stream (proven
    // FETCH 113->38 MB). Kept even though wall-time-neutral: it derisks latency.
    const int bpe = N / MT;                    // blocks per ensemble (512)
    const int e = bid / bpe, n0 = (bid - e * bpe) * MT;

    // zero ONLY the K-pad cols: [38,64) and [208,232). All other cols are written
    // (staged or epilogue) before any read. Pad cols survive all layers untouched.
    for (int t = tid; t < MT * 13; t += 256) {
        int row = t / 13, k = t - row * 13;
        *((unsigned*)(hA + row * HS + 38 + 2 * k)) = 0u;
    }
    for (int t = tid; t < MT * 12; t += 256) {
        int row = t / 12, k = t - row * 12;
        *((unsigned*)(hA + row * HS + 208 + 2 * k)) = 0u;
    }

    // stage x = concat(s, a) -> hA cols 0..37 as 19 packed bf16 pairs per row.
    // R12: float2 load + pk2 + u32 store (5 instrs/thread vs 30 scalar).
    // Pair idx 0..14 lies fully in s (cols 0..29), 15..18 fully in a (cols 30..37);
    // both bases are 8B-aligned ((g*7+e)*120 and (g*7+e)*32).
    {
        int m = tid & 63, cg = tid >> 6;
        long g = n0 + m;
        const float* srow = s + (g * ENS + e) * SDIM;
        const float* arow = a + (g * ENS + e) * ADIM;
#pragma unroll
        for (int k = 0; k < 5; k++) {
            int idx = cg * 5 + k;
            if (idx < 19) {
                float2 p = (idx < 15) ? *((const float2*)(srow + 2 * idx))
                                      : *((const float2*)(arow + 2 * (idx - 15)));
                *((unsigned*)(hA + m * HS + 2 * idx)) = pk2(p.x, p.y);
            }
        }
    }
    __syncthreads();

    // wave-uniform fragment base pointers (SGPR; per-lane part is `lo`)
    const unsigned short* we = ws + e * PER_E;
    const unsigned short* L1o = we + swv * 3 * 2 * 512;
    const unsigned short* L1s = we + 12 * 2 * 512;
    const unsigned short* H0o = we + U_L1 + swv * 3 * 7 * 512;
    const unsigned short* H0s = we + U_L1 + 12 * 7 * 512;
    const unsigned short* H1o = H0o + U_H;
    const unsigned short* H1s = H0s + U_H;
    const unsigned short* H2o = H1o + U_H;
    const unsigned short* H2s = H1s + U_H;
    const unsigned short* HDo = we + OFF_HD2 + swv * 7 * 512;

    f32x4 accO[4][3];   // own col-tiles: [row-tile][c]
    f32x4 accS;         // shared ct12, row-tile = swv
    bf16x8 bqA[4], bqB[4];   // ping-pong weight fragment buffers
    f32x4 iO[3];        // bias-init for own col-tiles (col-dependent only, same all r)
    f32x4 iS;           // bias-init for shared ct12 (cols >= HID -> 0 keeps K-pad)

    // load the CURRENT layer's bias into iO/iS; issued before the preceding epilogue
    // so L2 latency hides under ~1000 cyc of swish VALU.
    auto loadBias = [&](const float* bias) {
#pragma unroll
        for (int c = 0; c < 3; c++)
            *((float4*)&iO[c]) = *((const float4*)(bias + (3 * swv + c) * 16 + quad * 4));
        int col = 192 + quad * 4;
        iS = (f32x4){0.f, 0.f, 0.f, 0.f};
        if (col < HID) *((float4*)&iS) = *((const float4*)(bias + col));   // quad 0,1 only
    };

    // swish (bias already in acc) -> hA. Own cts: col < 192 always.
    // Shared ct12: cols 192..207; pad cols (>=200) had zero weights+bias -> writes 0.
    auto epiH = [&]() {
#pragma unroll
        for (int c = 0; c < 3; c++) {
            int col = (3 * swv + c) * 16 + quad * 4;
#pragma unroll
            for (int r = 0; r < 4; r++) {
                float v0 = accO[r][c][0], v1 = accO[r][c][1];
                float v2 = accO[r][c][2], v3 = accO[r][c][3];
                v0 *= __builtin_amdgcn_rcpf(1.f + __expf(-v0));
                v1 *= __builtin_amdgcn_rcpf(1.f + __expf(-v1));
                v2 *= __builtin_amdgcn_rcpf(1.f + __expf(-v2));
                v3 *= __builtin_amdgcn_rcpf(1.f + __expf(-v3));
                *((uint2*)(hA + (r * 16 + l16) * HS + col)) = make_uint2(pk2(v0, v1), pk2(v2, v3));
            }
        }
        {
            int col = 192 + quad * 4;
            float v0 = accS[0], v1 = accS[1], v2 = accS[2], v3 = accS[3];
            v0 *= __builtin_amdgcn_rcpf(1.f + __expf(-v0));
            v1 *= __builtin_amdgcn_rcpf(1.f + __expf(-v1));
            v2 *= __builtin_amdgcn_rcpf(1.f + __expf(-v2));
            v3 *= __builtin_amdgcn_rcpf(1.f + __expf(-v3));
            *((uint2*)(hA + (swv * 16 + l16) * HS + col)) = make_uint2(pk2(v0, v1), pk2(v2, v3));
        }
    };

    // initial fragment load (L1, st=0) -> bqA ; L1 bias -> iO/iS
    loadBias(b1 + e * HID);
#pragma unroll
    for (int c = 0; c < 3; c++) bqA[c] = *((const bf16x8*)(L1o + (c * 2) * 512 + lo));
    bqA[3] = *((const bf16x8*)(L1s + lo));

    // Buffer parity chain: L1(S=2) in A out A; each S=7 layer flips.
    runLayer<2, 3, true, 7, 3, true>(L1o, L1s, H0o, H0s, hA, lo, swv, l16, quad, accO, accS, bqA, bqB, iO, iS);
    __syncthreads();
    loadBias(bh + (0 * ENS + e) * HID);
    epiH();
    __syncthreads();
    runLayer<7, 3, true, 7, 3, true>(H0o, H0s, H1o, H1s, hA, lo, swv, l16, quad, accO, accS, bqA, bqB, iO, iS);
    __syncthreads();
    loadBias(bh + (1 * ENS + e) * HID);
    epiH();
    __syncthreads();
    runLayer<7, 3, true, 7, 3, true>(H1o, H1s, H2o, H2s, hA, lo, swv, l16, quad, accO, accS, bqB, bqA, iO, iS);
    __syncthreads();
    loadBias(bh + (2 * ENS + e) * HID);
    epiH();
    __syncthreads();
    runLayer<7, 3, true, 7, 1, false>(H2o, H2s, HDo, (const unsigned short*)nullptr,
                                      hA, lo, swv, l16, quad, accO, accS, bqA, bqB, iO, iS);
    __syncthreads();

    // head bias + sigma clamp params, loaded before the last epilogue (latency hidden)
    const bool isSig = (swv >= 2);
    const int c0 = (swv & 1) * 16 + quad * 4;
    {
        f32x4 iH = (f32x4){0.f, 0.f, 0.f, 0.f};
        const float* hb = isSig ? bsig : bmu;
#pragma unroll
        for (int i = 0; i < 4; i++)
            if (c0 + i < DOUT) iH[i] = hb[e * DOUT + c0 + i];
        iO[0] = iH;
        iO[1] = (f32x4){0.f, 0.f, 0.f, 0.f};
        iO[2] = (f32x4){0.f, 0.f, 0.f, 0.f};
        iS = (f32x4){0.f, 0.f, 0.f, 0.f};
    }
    float mx_i[4], mn_i[4];
#pragma unroll
    for (int i = 0; i < 4; i++) {
        int c = c0 + i;
        if (isSig) {
            mx_i[i] = (c < SDIM) ? maxs[c] : maxr[0];
            mn_i[i] = (c < SDIM) ? mins[c] : minr[0];
        } else { mx_i[i] = 0.f; mn_i[i] = 0.f; }
    }
    epiH();   // bh2 epilogue
    __syncthreads();
    runLayer<7, 1, false, 0, 0, false>(HDo, (const unsigned short*)nullptr,
                                       (const unsigned short*)nullptr, (const unsigned short*)nullptr,
                                       hA, lo, swv, l16, quad, accO, accS, bqB, bqA, iO, iS);
    // no barrier: head tail reads only registers, writes only global

    // head tail: wave owns ct = swv -> lane holds cols swv*16+quad*4+{0..3}
    // (mu block 0..31 for swv<2, sigma block 32..63 for swv>=2), rows r*16+l16.
    // Bias already folded into acc init.
    const long off1 = (long)N * ENS * SDIM;    // ds_sg
    const long off2 = 2 * off1;                // r_mu
    const long off3 = off2 + (long)N * ENS;    // r_sg
#pragma unroll
    for (int r = 0; r < 4; r++) {
        long g = n0 + r * 16 + l16;
        long rowbase = (g * ENS + e) * SDIM;
#pragma unroll
        for (int i = 0; i < 4; i++) {
            int c = c0 + i;
            if (c < DOUT) {
                float v = accO[r][0][i];
                if (!isSig) {
                    if (c < SDIM) out[rowbase + c] = v;
                    else out[off2 + g * ENS + e] = v;
                } else {
                    v = 0.5f * (mx_i[i] - softplusf(mx_i[i] - 2.f * v));
                    v = 0.5f * (mn_i[i] + softplusf(2.f * v - mn_i[i]));
                    v = __expf(v);
                    if (c < SDIM) out[off1 + rowbase + c] = v;
                    else out[off3 + g * ENS + e] = v;
                }
            }
        }
    }
}

extern "C" void kernel_launch(void* const* d_in, const int* in_sizes, int n_in,
                              void* d_out, int out_size, void* d_ws, size_t ws_size,
                              hipStream_t stream) {
    const float* s    = (const float*)d_in[0];
    const float* a    = (const float*)d_in[1];
    const float* W1   = (const float*)d_in[2];
    const float* b1   = (const float*)d_in[3];
    const float* Wh   = (const float*)d_in[4];
    const float* bh   = (const float*)d_in[5];
    const float* Wmu  = (const float*)d_in[6];
    const float* bmu  = (const float*)d_in[7];
    const float* Wsig = (const float*)d_in[8];
    const float* bsig = (const float*)d_in[9];
    const float* maxs = (const float*)d_in[10];
    const float* mins = (const float*)d_in[11];
    const float* maxr = (const float*)d_in[12];
    const float* minr = (const float*)d_in[13];
    float* out = (float*)d_out;
    unsigned short* ws = (unsigned short*)d_ws;

    int N = in_sizes[0] / (ENS * SDIM);        // 32768

    int prepBlocks = (WS_TOTAL + 255) / 256;
    prep_kernel<<<prepBlocks, 256, 0, stream>>>(W1, Wh, Wmu, Wsig, ws);

    int mainBlocks = (N / MT) * ENS;           // 3584
    ens_mlp_kernel<<<mainBlocks, 256, 0, stream>>>(s, a, b1, bh, bmu, bsig,
                                                   maxs, mins, maxr, minr, ws, out, N);
}